// Round 17
// baseline (386.604 us; speedup 1.0000x reference)
//
#include <hip/hip_runtime.h>
#include <hip/hip_bf16.h>

#define EMBED 1024
#define HEADS 16
#define HEAD_DIM 64
#define FFDIM 4096
#define TSEQ 2048
#define BATCH 4
#define ROWS (BATCH * TSEQ)  // 8192

typedef __bf16 bf16;
typedef __attribute__((ext_vector_type(8))) __bf16 bf16x8;
typedef __attribute__((ext_vector_type(4))) __bf16 bf16x4;
typedef __attribute__((ext_vector_type(4))) float f32x4;
typedef __attribute__((ext_vector_type(16))) float f32x16;

typedef const __attribute__((address_space(1))) void* gvp;
typedef __attribute__((address_space(3))) void* svp;

__device__ inline unsigned pk2(float a, float b) {
  union { bf16 h[2]; unsigned u; } x;
  x.h[0] = (bf16)a;
  x.h[1] = (bf16)b;
  return x.u;
}

// ---------------- weight conversion (LDS-tiled transposes, coalesced) ----------------
__global__ __launch_bounds__(256) void conv_wqkv_t(
    const float* __restrict__ Wq, const float* __restrict__ Wk,
    const float* __restrict__ Wv, bf16* __restrict__ WqkvT) {
  __shared__ bf16 t[64][72];
  int tid = threadIdx.x;
  int k0 = blockIdx.x * 64;  // c-tile
  int head = blockIdx.y;
  int which = blockIdx.z;
  const float* src = which == 0 ? Wq : which == 1 ? Wk : Wv;
  float scale = which == 0 ? 0.125f * 1.44269504088896f : 1.0f;
  src += (size_t)head * 65536;
  bf16* dst = WqkvT + ((size_t)which * 1024 + head * 64) * 1024;
#pragma unroll
  for (int i = 0; i < 4; ++i) {
    int r = i * 16 + (tid >> 4);  // c within tile
    int c = (tid & 15) * 4;       // d
    float4 v = *(const float4*)&src[(size_t)(k0 + r) * 64 + c];
    t[c + 0][r] = (bf16)(v.x * scale);
    t[c + 1][r] = (bf16)(v.y * scale);
    t[c + 2][r] = (bf16)(v.z * scale);
    t[c + 3][r] = (bf16)(v.w * scale);
  }
  __syncthreads();
#pragma unroll
  for (int i = 0; i < 2; ++i) {
    int r = i * 32 + (tid >> 3);  // d row
    int c = (tid & 7) * 8;        // c col
    bf16x8 o;
#pragma unroll
    for (int j = 0; j < 8; ++j) o[j] = t[r][c + j];
    *(bf16x8*)&dst[(size_t)r * 1024 + k0 + c] = o;
  }
}

// W [K,N] fp32 -> WT [N,K] bf16, tiled 64x64
__global__ __launch_bounds__(256) void transpose_conv(
    const float* __restrict__ W, bf16* __restrict__ WT, int K, int N) {
  __shared__ bf16 t[64][72];
  int tid = threadIdx.x;
  int n0 = blockIdx.x * 64, k0 = blockIdx.y * 64;
#pragma unroll
  for (int i = 0; i < 4; ++i) {
    int r = i * 16 + (tid >> 4);  // k
    int c = (tid & 15) * 4;       // n
    float4 v = *(const float4*)&W[(size_t)(k0 + r) * N + n0 + c];
    t[c + 0][r] = (bf16)v.x;
    t[c + 1][r] = (bf16)v.y;
    t[c + 2][r] = (bf16)v.z;
    t[c + 3][r] = (bf16)v.w;
  }
  __syncthreads();
#pragma unroll
  for (int i = 0; i < 2; ++i) {
    int r = i * 32 + (tid >> 3);  // n
    int c = (tid & 7) * 8;        // k
    bf16x8 o;
#pragma unroll
    for (int j = 0; j < 8; ++j) o[j] = t[r][c + j];
    *(bf16x8*)&WT[(size_t)(n0 + r) * K + k0 + c] = o;
  }
}

// v [B,H,T,Dh] bf16 -> vt [B,H,Dh,T] bf16, per-bh 64x64 tiles
__global__ __launch_bounds__(256) void transpose_v(const bf16* __restrict__ v,
                                                   bf16* __restrict__ vt) {
  __shared__ bf16 t[64][72];
  int bh = blockIdx.y;
  int t0 = blockIdx.x * 64;
  const bf16* src = v + (size_t)bh * 131072;
  bf16* dst = vt + (size_t)bh * 131072;
  int tid = threadIdx.x;
#pragma unroll
  for (int i = 0; i < 2; ++i) {
    int c = tid + i * 256;
    int r = c >> 3, d0 = (c & 7) * 8;
    bf16x8 vv = *(const bf16x8*)&src[(size_t)(t0 + r) * 64 + d0];
#pragma unroll
    for (int j = 0; j < 8; ++j) t[d0 + j][r] = vv[j];
  }
  __syncthreads();
#pragma unroll
  for (int i = 0; i < 2; ++i) {
    int c = tid + i * 256;
    int r = c >> 3, s0 = (c & 7) * 8;
    bf16x8 o;
#pragma unroll
    for (int j = 0; j < 8; ++j) o[j] = t[r][s0 + j];
    *(bf16x8*)&dst[(size_t)r * 2048 + t0 + s0] = o;
  }
}

// ---------------- layernorm (fp32 in -> bf16 out) ----------------
__global__ __launch_bounds__(256) void ln_kernel(
    const float* __restrict__ x, const float* __restrict__ g,
    const float* __restrict__ bta, bf16* __restrict__ out) {
  int row = blockIdx.x;
  const float* xr = x + (size_t)row * EMBED;
  float4 v = ((const float4*)xr)[threadIdx.x];
  float s1 = v.x + v.y + v.z + v.w;
  float s2 = v.x * v.x + v.y * v.y + v.z * v.z + v.w * v.w;
#pragma unroll
  for (int off = 1; off < 64; off <<= 1) {
    s1 += __shfl_xor(s1, off);
    s2 += __shfl_xor(s2, off);
  }
  __shared__ float red[8];
  int wid = threadIdx.x >> 6;
  int lane = threadIdx.x & 63;
  if (lane == 0) {
    red[wid * 2] = s1;
    red[wid * 2 + 1] = s2;
  }
  __syncthreads();
  s1 = red[0] + red[2] + red[4] + red[6];
  s2 = red[1] + red[3] + red[5] + red[7];
  float mu = s1 * (1.0f / EMBED);
  float var = s2 * (1.0f / EMBED) - mu * mu;
  float rs = rsqrtf(var + 1e-5f);
  float4 gv = ((const float4*)g)[threadIdx.x];
  float4 bv = ((const float4*)bta)[threadIdx.x];
  bf16x4 o;
  o[0] = (bf16)((v.x - mu) * rs * gv.x + bv.x);
  o[1] = (bf16)((v.y - mu) * rs * gv.y + bv.y);
  o[2] = (bf16)((v.z - mu) * rs * gv.z + bv.z);
  o[3] = (bf16)((v.w - mu) * rs * gv.w + bv.w);
  *(bf16x4*)(out + (size_t)row * EMBED + threadIdx.x * 4) = o;
}

// ---------------- 256x256 GEMM, BK=32, 3 LDS buffers, 2-phase interleave ----------------
// LDS swizzle: slot ^= (row>>1)&3 -> ds_read_b128 bank-group = 4*(row&1) +
// lg^((row>>1)&3), distinct for all 8 row-residues => 2 lanes/group (free).
template <int EPI>
__global__ __launch_bounds__(512, 1) void gemm256(
    const bf16* __restrict__ A, const bf16* __restrict__ BT,
    bf16* __restrict__ Cb, const float* __restrict__ bias, int M, int N,
    int K) {
  __shared__ __attribute__((aligned(16))) char lds[98304];  // 3 x (A16K + B16K)
  int gx = gridDim.x;
  int nwg = gx * gridDim.y;
  int wgid = blockIdx.y * gx + blockIdx.x;
  int cpx = nwg >> 3;
  int swz = (wgid & 7) * cpx + (wgid >> 3);
  int m0 = (swz / gx) * 256, n0 = (swz % gx) * 256;
  int tid = threadIdx.x;
  int lane = tid & 63, wid = tid >> 6;
  int lr = lane & 15, lg = lane >> 4;
  int wrM = (wid >> 2) * 128;  // wave M base: 0 or 128
  int wcN = (wid & 3) * 64;    // wave N base: 0/64/128/192
  int crow = lane >> 2;        // staging row within 16-row chunk
  int slotg = (lane & 3) ^ ((crow >> 1) & 3);  // inverse-swizzled global slot
  int NT = K >> 5;
  size_t rb = (size_t)K * 2;  // bytes per row of A / BT

  auto stageA = [&](int t) {
    char* dst = lds + ((unsigned)t % 3u) * 32768u;
#pragma unroll
    for (int q = 0; q < 2; ++q) {
      int c = wid * 2 + q;  // chunk 0..15 (16 rows each)
      const char* srcA = (const char*)A + (size_t)(m0 + c * 16 + crow) * rb +
                         (size_t)t * 64 + slotg * 16;
      __builtin_amdgcn_global_load_lds((gvp)srcA, (svp)(dst + c * 1024), 16, 0,
                                       0);
    }
  };
  auto stageB = [&](int t) {
    char* dst = lds + ((unsigned)t % 3u) * 32768u + 16384u;
#pragma unroll
    for (int q = 0; q < 2; ++q) {
      int c = wid * 2 + q;
      const char* srcB = (const char*)BT + (size_t)(n0 + c * 16 + crow) * rb +
                         (size_t)t * 64 + slotg * 16;
      __builtin_amdgcn_global_load_lds((gvp)srcB, (svp)(dst + c * 1024), 16, 0,
                                       0);
    }
  };

  stageA(0);
  stageB(0);
  stageA(1);
  stageB(1);
  f32x4 acc[8][4] = {};
  int swcol = ((lg ^ ((lr >> 1) & 3)) * 16);
  for (int t = 0; t < NT; ++t) {
    if (t == NT - 1)
      asm volatile("s_waitcnt vmcnt(0)" ::: "memory");
    else
      asm volatile("s_waitcnt vmcnt(4)" ::: "memory");
    __builtin_amdgcn_s_barrier();
    __builtin_amdgcn_sched_barrier(0);
    const char* Ab = lds + ((unsigned)t % 3u) * 32768u;
    const char* Bb = Ab + 16384;
    int tn = t + 2;
    bool st = tn < NT;
    // ---- phase A ----
    bf16x8 bfr[4], afA[4], afB[4];
#pragma unroll
    for (int j = 0; j < 4; ++j)
      bfr[j] = *(const bf16x8*)(Bb + (wcN + j * 16 + lr) * 64 + swcol);
#pragma unroll
    for (int i = 0; i < 4; ++i)
      afA[i] = *(const bf16x8*)(Ab + (wrM + i * 16 + lr) * 64 + swcol);
    if (st) stageA(tn);
    __builtin_amdgcn_s_barrier();
    __builtin_amdgcn_sched_barrier(0);
    __builtin_amdgcn_s_setprio(1);
#pragma unroll
    for (int i = 0; i < 4; ++i)
#pragma unroll
      for (int j = 0; j < 4; ++j)
        acc[i][j] = __builtin_amdgcn_mfma_f32_16x16x32_bf16(afA[i], bfr[j],
                                                            acc[i][j], 0, 0, 0);
    __builtin_amdgcn_s_setprio(0);
    __builtin_amdgcn_sched_barrier(0);
    // ---- phase B ----
#pragma unroll
    for (int i = 0; i < 4; ++i)
      afB[i] = *(const bf16x8*)(Ab + (wrM + 64 + i * 16 + lr) * 64 + swcol);
    if (st) stageB(tn);
    __builtin_amdgcn_s_barrier();
    __builtin_amdgcn_sched_barrier(0);
    __builtin_amdgcn_s_setprio(1);
#pragma unroll
    for (int i = 0; i < 4; ++i)
#pragma unroll
      for (int j = 0; j < 4; ++j)
        acc[4 + i][j] = __builtin_amdgcn_mfma_f32_16x16x32_bf16(
            afB[i], bfr[j], acc[4 + i][j], 0, 0, 0);
    __builtin_amdgcn_s_setprio(0);
    __builtin_amdgcn_sched_barrier(0);
  }
#pragma unroll
  for (int i = 0; i < 8; ++i) {
#pragma unroll
    for (int j = 0; j < 4; ++j) {
#pragma unroll
      for (int r = 0; r < 4; ++r) {
        int row = m0 + wrM + i * 16 + lg * 4 + r;
        int col = n0 + wcN + j * 16 + lr;
        float v = acc[i][j][r];
        if (EPI == 0) {
          int which = col >> 10, cc = col & 1023;
          int b = row >> 11, tt = row & 2047, h = cc >> 6, d = cc & 63;
          bf16* dst = Cb + (size_t)which * 8388608;
          dst[((size_t)((b << 4) + h) * TSEQ + tt) * HEAD_DIM + d] = (bf16)v;
        } else {
          size_t o = (size_t)row * N + col;
          float u = v + bias[col];
          Cb[o] = (bf16)(u > 0.f ? u : 0.f);
        }
      }
    }
  }
}

// ---------------- 256x128 GEMM + residual epilogue (fp32 out), 2-phase pipeline ----------
__global__ __launch_bounds__(512, 2) void gemm_res(
    const bf16* __restrict__ A, const bf16* __restrict__ BT,
    float* __restrict__ Cf, const float* __restrict__ bias,
    const float* __restrict__ resid, int M, int N, int K) {
  __shared__ __attribute__((aligned(16))) char lds[73728];  // 3 x 24KB
  int gx = gridDim.x;
  int nwg = gx * gridDim.y;
  int wgid = blockIdx.y * gx + blockIdx.x;
  int cpx = nwg >> 3;
  int swz = (wgid & 7) * cpx + (wgid >> 3);
  int m0 = (swz / gx) * 256, n0 = (swz % gx) * 128;
  int tid = threadIdx.x;
  int lane = tid & 63, wid = tid >> 6;
  int lr = lane & 15, lg = lane >> 4;
  int wrM = (wid >> 1) * 64;  // wave M base: 0/64/128/192
  int wcN = (wid & 1) * 64;   // wave N base: 0/64
  int crow = lane >> 2;
  int slotg = (lane & 3) ^ ((crow >> 1) & 3);
  int NT = K >> 5;
  size_t rb = (size_t)K * 2;

  auto stageA = [&](int t) {
    char* dst = lds + ((unsigned)t % 3u) * 24576u;
#pragma unroll
    for (int q = 0; q < 2; ++q) {
      int c = wid * 2 + q;  // chunk 0..15 (16 rows each)
      const char* srcA = (const char*)A + (size_t)(m0 + c * 16 + crow) * rb +
                         (size_t)t * 64 + slotg * 16;
      __builtin_amdgcn_global_load_lds((gvp)srcA, (svp)(dst + c * 1024), 16, 0,
                                       0);
    }
  };
  auto stageB = [&](int t) {
    char* dst = lds + ((unsigned)t % 3u) * 24576u + 16384u;
    const char* srcB = (const char*)BT + (size_t)(n0 + wid * 16 + crow) * rb +
                       (size_t)t * 64 + slotg * 16;
    __builtin_amdgcn_global_load_lds((gvp)srcB, (svp)(dst + wid * 1024), 16, 0,
                                     0);
  };

  stageA(0);
  stageB(0);
  stageA(1);
  stageB(1);
  f32x4 acc[4][4] = {};
  int swcol = ((lg ^ ((lr >> 1) & 3)) * 16);
  for (int t = 0; t < NT; ++t) {
    if (t == NT - 1)
      asm volatile("s_waitcnt vmcnt(0)" ::: "memory");
    else
      asm volatile("s_waitcnt vmcnt(3)" ::: "memory");
    __builtin_amdgcn_s_barrier();
    __builtin_amdgcn_sched_barrier(0);
    const char* Ab = lds + ((unsigned)t % 3u) * 24576u;
    const char* Bb = Ab + 16384;
    int tn = t + 2;
    bool st = tn < NT;
    // ---- phase A ----
    bf16x8 bfr[4], afA[2], afB[2];
#pragma unroll
    for (int j = 0; j < 4; ++j)
      bfr[j] = *(const bf16x8*)(Bb + (wcN + j * 16 + lr) * 64 + swcol);
#pragma unroll
    for (int i = 0; i < 2; ++i)
      afA[i] = *(const bf16x8*)(Ab + (wrM + i * 16 + lr) * 64 + swcol);
    if (st) stageA(tn);
    __builtin_amdgcn_s_barrier();
    __builtin_amdgcn_sched_barrier(0);
    __builtin_amdgcn_s_setprio(1);
#pragma unroll
    for (int i = 0; i < 2; ++i)
#pragma unroll
      for (int j = 0; j < 4; ++j)
        acc[i][j] = __builtin_amdgcn_mfma_f32_16x16x32_bf16(afA[i], bfr[j],
                                                            acc[i][j], 0, 0, 0);
    __builtin_amdgcn_s_setprio(0);
    __builtin_amdgcn_sched_barrier(0);
    // ---- phase B ----
#pragma unroll
    for (int i = 0; i < 2; ++i)
      afB[i] = *(const bf16x8*)(Ab + (wrM + 32 + i * 16 + lr) * 64 + swcol);
    if (st) stageB(tn);
    __builtin_amdgcn_s_barrier();
    __builtin_amdgcn_sched_barrier(0);
    __builtin_amdgcn_s_setprio(1);
#pragma unroll
    for (int i = 0; i < 2; ++i)
#pragma unroll
      for (int j = 0; j < 4; ++j)
        acc[2 + i][j] = __builtin_amdgcn_mfma_f32_16x16x32_bf16(
            afB[i], bfr[j], acc[2 + i][j], 0, 0, 0);
    __builtin_amdgcn_s_setprio(0);
    __builtin_amdgcn_sched_barrier(0);
  }
#pragma unroll
  for (int i = 0; i < 4; ++i) {
#pragma unroll
    for (int j = 0; j < 4; ++j) {
#pragma unroll
      for (int r = 0; r < 4; ++r) {
        int row = m0 + wrM + i * 16 + lg * 4 + r;
        int col = n0 + wcN + j * 16 + lr;
        size_t o = (size_t)row * N + col;
        Cf[o] = resid[o] + bias[col] + acc[i][j][r];
      }
    }
  }
}

// ---------------- causal flash attention: QBLK=64, 2 waves, swapped-QK 32x32,
// in-register P, HW permlane32_swap. Small blocks -> high occupancy ------------------
// grid (64, 32) x 128 threads: x = bh (XCD L2 locality), y -> Q = 31-y.
__global__ __launch_bounds__(128) void attn_kernel(
    const bf16* __restrict__ q, const bf16* __restrict__ k,
    const bf16* __restrict__ vt, bf16* __restrict__ out) {
  __shared__ __attribute__((aligned(16))) char ldsK[8192];
  __shared__ __attribute__((aligned(16))) char ldsV[8192];
  int bh = blockIdx.x;
  int b = bh >> 4, h = bh & 15;
  const bf16* qb = q + (size_t)bh * TSEQ * HEAD_DIM;
  const bf16* kb = k + (size_t)bh * TSEQ * HEAD_DIM;
  const bf16* vb = vt + (size_t)bh * HEAD_DIM * TSEQ;
  int tid = threadIdx.x, lane = tid & 63, w = tid >> 6;  // w in 0,1
  int l31 = lane & 31, hi = lane >> 5;
  int Q = 31 - blockIdx.y;    // tile of 64 q-rows; longest job first
  int tw = Q * 64 + w * 32;   // wave's 32 q-rows
  int qrow = tw + l31;        // this lane's q-row (swapped layout)
  int srow0 = tid >> 3;       // staging rows 0..15 (+16/+32/+48)
  int scol = (tid & 7) * 16;  // byte col
  int swz31 = (l31 & 7) << 4; // read-side swizzle for rows l31 / 32+l31
  bf16x8 aq[4];
#pragma unroll
  for (int f = 0; f < 4; ++f)
    aq[f] = *(const bf16x8*)&qb[(size_t)qrow * HEAD_DIM + f * 16 + hi * 8];
  f32x16 o0 = {}, o1 = {};
  f32x16 minit;
#pragma unroll
  for (int i = 0; i < 16; ++i) minit[i] = -8.0f;  // softmax shift in C-init
  float sacc = 0.f;
  int nj = Q + 1;
  for (int j = 0; j < nj; ++j) {
#pragma unroll
    for (int i = 0; i < 4; ++i) {
      int rr = srow0 + i * 16;
      int sw = scol ^ ((rr & 7) << 4);
      *(bf16x8*)(ldsK + rr * 128 + sw) =
          *(const bf16x8*)&kb[(size_t)(j * 64 + rr) * HEAD_DIM + (scol >> 1)];
      *(bf16x8*)(ldsV + rr * 128 + sw) =
          *(const bf16x8*)&vb[(size_t)rr * TSEQ + j * 64 + (scol >> 1)];
    }
    __syncthreads();
    f32x16 s0 = minit, s1 = minit;
    __builtin_amdgcn_s_setprio(1);
#pragma unroll
    for (int f = 0; f < 4; ++f) {
      int colb = (f * 32 + hi * 16) ^ swz31;
      bf16x8 ka = *(const bf16x8*)(ldsK + l31 * 128 + colb);
      bf16x8 kb2 = *(const bf16x8*)(ldsK + (32 + l31) * 128 + colb);
      s0 = __builtin_amdgcn_mfma_f32_32x32x16_bf16(ka, aq[f], s0, 0, 0, 0);
      s1 = __builtin_amdgcn_mfma_f32_32x32x16_bf16(kb2, aq[f], s1, 0, 0, 0);
    }
    __builtin_amdgcn_s_setprio(0);
    if (j == Q) {  // causal mask on the boundary tile
#pragma unroll
      for (int reg = 0; reg < 16; ++reg) {
        int key = j * 64 + (reg & 3) + 8 * (reg >> 2) + 4 * hi;
        if (key > qrow) s0[reg] = -1e30f;
        if (key + 32 > qrow) s1[reg] = -1e30f;
      }
    }
    unsigned pk0[8], pk1[8];
#pragma unroll
    for (int p = 0; p < 8; ++p) {
      float a0 = exp2f(s0[2 * p]), b0 = exp2f(s0[2 * p + 1]);
      float a1 = exp2f(s1[2 * p]), b1 = exp2f(s1[2 * p + 1]);
      sacc += (a0 + b0) + (a1 + b1);
      pk0[p] = pk2(a0, b0);
      pk1[p] = pk2(a1, b1);
    }
    // Half-exchange via HW permlane32_swap (VALU crossbar, no LDS):
    // swap(x0,x2): x0' = [own_lo | partner_lo], x2' = [partner_hi | own_hi].
    __builtin_amdgcn_s_setprio(1);
#pragma unroll
    for (int ks = 0; ks < 4; ++ks) {
      const unsigned* P = (ks >> 1) ? pk1 : pk0;
      int kp = (ks & 1) * 4;
      unsigned x0 = P[kp + 0], x1 = P[kp + 1];
      unsigned x2 = P[kp + 2], x3 = P[kp + 3];
      asm("v_permlane32_swap_b32 %0, %1" : "+v"(x0), "+v"(x2));
      asm("v_permlane32_swap_b32 %0, %1" : "+v"(x1), "+v"(x3));
      union { unsigned u[4]; bf16x8 v; } pa;
      pa.u[0] = x0;
      pa.u[1] = x1;
      pa.u[2] = x2;
      pa.u[3] = x3;
      int colb = (ks * 32 + hi * 16) ^ swz31;
      bf16x8 bv0 = *(const bf16x8*)(ldsV + l31 * 128 + colb);
      bf16x8 bv1 = *(const bf16x8*)(ldsV + (32 + l31) * 128 + colb);
      o0 = __builtin_amdgcn_mfma_f32_32x32x16_bf16(pa.v, bv0, o0, 0, 0, 0);
      o1 = __builtin_amdgcn_mfma_f32_32x32x16_bf16(pa.v, bv1, o1, 0, 0, 0);
    }
    __builtin_amdgcn_s_setprio(0);
    __syncthreads();
  }
  float tot = sacc + __shfl_xor(sacc, 32);
#pragma unroll
  for (int reg = 0; reg < 16; ++reg) {
    int ql = (reg & 3) + 8 * (reg >> 2) + 4 * hi;
    float lw = __shfl(tot, ql);
    float rl = 1.0f / lw;
    int t = tw + ql;
    size_t o = ((size_t)(b * TSEQ) + t) * EMBED + h * HEAD_DIM;
    out[o + l31] = (bf16)(o0[reg] * rl);
    out[o + 32 + l31] = (bf16)(o1[reg] * rl);
  }
}

// ---------------- launch ----------------
extern "C" void kernel_launch(void* const* d_in, const int* in_sizes, int n_in,
                              void* d_out, int out_size, void* d_ws,
                              size_t ws_size, hipStream_t stream) {
  const float* x = (const float*)d_in[0];
  const float* Wq = (const float*)d_in[1];
  const float* Wk = (const float*)d_in[2];
  const float* Wv = (const float*)d_in[3];
  const float* Wo = (const float*)d_in[4];
  const float* bo = (const float*)d_in[5];
  const float* W1 = (const float*)d_in[6];
  const float* b1 = (const float*)d_in[7];
  const float* W2 = (const float*)d_in[8];
  const float* b2 = (const float*)d_in[9];
  const float* g1 = (const float*)d_in[10];
  const float* be1 = (const float*)d_in[11];
  const float* g2 = (const float*)d_in[12];
  const float* be2 = (const float*)d_in[13];
  float* out = (float*)d_out;
  char* ws = (char*)d_ws;

  const size_t U = 16777216;  // 16 MiB
  bf16* h = (bf16*)(ws + 0 * U);
  bf16* qb = (bf16*)(ws + 1 * U);
  bf16* vtb = (bf16*)(ws + 0 * U);
  bf16* vnb = (bf16*)(ws + 3 * U);
  bf16* ao = (bf16*)(ws + 3 * U);
  float* x1 = (float*)(ws + 4 * U);
  bf16* h2 = (bf16*)(ws + 6 * U);
  bf16* ff1 = (bf16*)(ws + 0 * U);
  char* wbase = ws + 7 * U;
  bf16* WqkvT = (bf16*)(wbase);           // 6 MB
  bf16* WoT = (bf16*)(wbase + 6291456);   // 2 MB
  bf16* W1T = (bf16*)(wbase + 8388608);   // 8 MB
  bf16* W2T = (bf16*)(wbase + 16777216);  // 8 MB

  hipLaunchKernelGGL(conv_wqkv_t, dim3(16, 16, 3), dim3(256), 0, stream, Wq,
                     Wk, Wv, WqkvT);
  hipLaunchKernelGGL(transpose_conv, dim3(16, 16), dim3(256), 0, stream, Wo,
                     WoT, 1024, 1024);
  hipLaunchKernelGGL(transpose_conv, dim3(64, 16), dim3(256), 0, stream, W1,
                     W1T, 1024, 4096);
  hipLaunchKernelGGL(transpose_conv, dim3(16, 64), dim3(256), 0, stream, W2,
                     W2T, 4096, 1024);
  hipLaunchKernelGGL(ln_kernel, dim3(8192), dim3(256), 0, stream, x, g1, be1,
                     h);
  // fused QKV projection: 256x256 2-phase pipelined GEMM, scatter epilogue
  hipLaunchKernelGGL((gemm256<0>), dim3(12, 32), dim3(512), 0, stream, h,
                     WqkvT, qb, (const float*)nullptr, ROWS, 3072, 1024);
  // v [B,H,T,D] -> vt [B,H,D,T]
  hipLaunchKernelGGL(transpose_v, dim3(32, 64), dim3(256), 0, stream, vnb,
                     vtb);
  // attention (QBLK=64, 2-wave blocks for occupancy; swapped-QK 32x32)
  hipLaunchKernelGGL(attn_kernel, dim3(64, 32), dim3(128), 0, stream, qb,
                     qb + 8388608, vtb, ao);
  // x1 = x + ao @ Wo + bo : 256x128 pipelined GEMM with residual epilogue
  hipLaunchKernelGGL(gemm_res, dim3(8, 32), dim3(512), 0, stream, ao, WoT, x1,
                     bo, x, ROWS, 1024, 1024);
  // h2 = LN2(x1)
  hipLaunchKernelGGL(ln_kernel, dim3(8192), dim3(256), 0, stream, x1, g2, be2,
                     h2);
  // ff1 = relu(h2 @ W1 + b1): 256x256 2-phase pipelined GEMM
  hipLaunchKernelGGL((gemm256<3>), dim3(16, 32), dim3(512), 0, stream, h2, W1T,
                     ff1, b1, ROWS, 4096, 1024);
  // out = x1 + ff1 @ W2 + b2 : 256x128 pipelined GEMM with residual epilogue
  hipLaunchKernelGGL(gemm_res, dim3(8, 32), dim3(512), 0, stream, ff1, W2T,
                     out, b2, x1, ROWS, 1024, 4096);
}

// Round 18
// 379.158 us; speedup vs baseline: 1.0196x; 1.0196x over previous
//
#include <hip/hip_runtime.h>
#include <hip/hip_bf16.h>

#define EMBED 1024
#define HEADS 16
#define HEAD_DIM 64
#define FFDIM 4096
#define TSEQ 2048
#define BATCH 4
#define ROWS (BATCH * TSEQ)  // 8192

typedef __bf16 bf16;
typedef __attribute__((ext_vector_type(8))) __bf16 bf16x8;
typedef __attribute__((ext_vector_type(4))) __bf16 bf16x4;
typedef __attribute__((ext_vector_type(4))) float f32x4;
typedef __attribute__((ext_vector_type(16))) float f32x16;

typedef const __attribute__((address_space(1))) void* gvp;
typedef __attribute__((address_space(3))) void* svp;

__device__ inline unsigned pk2(float a, float b) {
  union { bf16 h[2]; unsigned u; } x;
  x.h[0] = (bf16)a;
  x.h[1] = (bf16)b;
  return x.u;
}

// ---------------- weight conversion (LDS-tiled transposes, coalesced) ----------------
__global__ __launch_bounds__(256) void conv_wqkv_t(
    const float* __restrict__ Wq, const float* __restrict__ Wk,
    const float* __restrict__ Wv, bf16* __restrict__ WqkvT) {
  __shared__ bf16 t[64][72];
  int tid = threadIdx.x;
  int k0 = blockIdx.x * 64;  // c-tile
  int head = blockIdx.y;
  int which = blockIdx.z;
  const float* src = which == 0 ? Wq : which == 1 ? Wk : Wv;
  float scale = which == 0 ? 0.125f * 1.44269504088896f : 1.0f;
  src += (size_t)head * 65536;
  bf16* dst = WqkvT + ((size_t)which * 1024 + head * 64) * 1024;
#pragma unroll
  for (int i = 0; i < 4; ++i) {
    int r = i * 16 + (tid >> 4);  // c within tile
    int c = (tid & 15) * 4;       // d
    float4 v = *(const float4*)&src[(size_t)(k0 + r) * 64 + c];
    t[c + 0][r] = (bf16)(v.x * scale);
    t[c + 1][r] = (bf16)(v.y * scale);
    t[c + 2][r] = (bf16)(v.z * scale);
    t[c + 3][r] = (bf16)(v.w * scale);
  }
  __syncthreads();
#pragma unroll
  for (int i = 0; i < 2; ++i) {
    int r = i * 32 + (tid >> 3);  // d row
    int c = (tid & 7) * 8;        // c col
    bf16x8 o;
#pragma unroll
    for (int j = 0; j < 8; ++j) o[j] = t[r][c + j];
    *(bf16x8*)&dst[(size_t)r * 1024 + k0 + c] = o;
  }
}

// W [K,N] fp32 -> WT [N,K] bf16, tiled 64x64
__global__ __launch_bounds__(256) void transpose_conv(
    const float* __restrict__ W, bf16* __restrict__ WT, int K, int N) {
  __shared__ bf16 t[64][72];
  int tid = threadIdx.x;
  int n0 = blockIdx.x * 64, k0 = blockIdx.y * 64;
#pragma unroll
  for (int i = 0; i < 4; ++i) {
    int r = i * 16 + (tid >> 4);  // k
    int c = (tid & 15) * 4;       // n
    float4 v = *(const float4*)&W[(size_t)(k0 + r) * N + n0 + c];
    t[c + 0][r] = (bf16)v.x;
    t[c + 1][r] = (bf16)v.y;
    t[c + 2][r] = (bf16)v.z;
    t[c + 3][r] = (bf16)v.w;
  }
  __syncthreads();
#pragma unroll
  for (int i = 0; i < 2; ++i) {
    int r = i * 32 + (tid >> 3);  // n
    int c = (tid & 7) * 8;        // k
    bf16x8 o;
#pragma unroll
    for (int j = 0; j < 8; ++j) o[j] = t[r][c + j];
    *(bf16x8*)&WT[(size_t)(n0 + r) * K + k0 + c] = o;
  }
}

// v [B,H,T,Dh] bf16 -> vt [B,H,Dh,T] bf16, per-bh 64x64 tiles
__global__ __launch_bounds__(256) void transpose_v(const bf16* __restrict__ v,
                                                   bf16* __restrict__ vt) {
  __shared__ bf16 t[64][72];
  int bh = blockIdx.y;
  int t0 = blockIdx.x * 64;
  const bf16* src = v + (size_t)bh * 131072;
  bf16* dst = vt + (size_t)bh * 131072;
  int tid = threadIdx.x;
#pragma unroll
  for (int i = 0; i < 2; ++i) {
    int c = tid + i * 256;
    int r = c >> 3, d0 = (c & 7) * 8;
    bf16x8 vv = *(const bf16x8*)&src[(size_t)(t0 + r) * 64 + d0];
#pragma unroll
    for (int j = 0; j < 8; ++j) t[d0 + j][r] = vv[j];
  }
  __syncthreads();
#pragma unroll
  for (int i = 0; i < 2; ++i) {
    int c = tid + i * 256;
    int r = c >> 3, s0 = (c & 7) * 8;
    bf16x8 o;
#pragma unroll
    for (int j = 0; j < 8; ++j) o[j] = t[r][s0 + j];
    *(bf16x8*)&dst[(size_t)r * 2048 + t0 + s0] = o;
  }
}

// ---------------- layernorm (fp32 in -> bf16 out) ----------------
__global__ __launch_bounds__(256) void ln_kernel(
    const float* __restrict__ x, const float* __restrict__ g,
    const float* __restrict__ bta, bf16* __restrict__ out) {
  int row = blockIdx.x;
  const float* xr = x + (size_t)row * EMBED;
  float4 v = ((const float4*)xr)[threadIdx.x];
  float s1 = v.x + v.y + v.z + v.w;
  float s2 = v.x * v.x + v.y * v.y + v.z * v.z + v.w * v.w;
#pragma unroll
  for (int off = 1; off < 64; off <<= 1) {
    s1 += __shfl_xor(s1, off);
    s2 += __shfl_xor(s2, off);
  }
  __shared__ float red[8];
  int wid = threadIdx.x >> 6;
  int lane = threadIdx.x & 63;
  if (lane == 0) {
    red[wid * 2] = s1;
    red[wid * 2 + 1] = s2;
  }
  __syncthreads();
  s1 = red[0] + red[2] + red[4] + red[6];
  s2 = red[1] + red[3] + red[5] + red[7];
  float mu = s1 * (1.0f / EMBED);
  float var = s2 * (1.0f / EMBED) - mu * mu;
  float rs = rsqrtf(var + 1e-5f);
  float4 gv = ((const float4*)g)[threadIdx.x];
  float4 bv = ((const float4*)bta)[threadIdx.x];
  bf16x4 o;
  o[0] = (bf16)((v.x - mu) * rs * gv.x + bv.x);
  o[1] = (bf16)((v.y - mu) * rs * gv.y + bv.y);
  o[2] = (bf16)((v.z - mu) * rs * gv.z + bv.z);
  o[3] = (bf16)((v.w - mu) * rs * gv.w + bv.w);
  *(bf16x4*)(out + (size_t)row * EMBED + threadIdx.x * 4) = o;
}

// ---------------- 256x256 GEMM, BK=32, 3 LDS buffers, 2-phase interleave ----------------
// LDS swizzle: slot ^= (row>>1)&3 -> ds_read_b128 bank-group = 4*(row&1) +
// lg^((row>>1)&3), distinct for all 8 row-residues => 2 lanes/group (free).
template <int EPI>
__global__ __launch_bounds__(512, 1) void gemm256(
    const bf16* __restrict__ A, const bf16* __restrict__ BT,
    bf16* __restrict__ Cb, const float* __restrict__ bias, int M, int N,
    int K) {
  __shared__ __attribute__((aligned(16))) char lds[98304];  // 3 x (A16K + B16K)
  int gx = gridDim.x;
  int nwg = gx * gridDim.y;
  int wgid = blockIdx.y * gx + blockIdx.x;
  int cpx = nwg >> 3;
  int swz = (wgid & 7) * cpx + (wgid >> 3);
  int m0 = (swz / gx) * 256, n0 = (swz % gx) * 256;
  int tid = threadIdx.x;
  int lane = tid & 63, wid = tid >> 6;
  int lr = lane & 15, lg = lane >> 4;
  int wrM = (wid >> 2) * 128;  // wave M base: 0 or 128
  int wcN = (wid & 3) * 64;    // wave N base: 0/64/128/192
  int crow = lane >> 2;        // staging row within 16-row chunk
  int slotg = (lane & 3) ^ ((crow >> 1) & 3);  // inverse-swizzled global slot
  int NT = K >> 5;
  size_t rb = (size_t)K * 2;  // bytes per row of A / BT

  auto stageA = [&](int t) {
    char* dst = lds + ((unsigned)t % 3u) * 32768u;
#pragma unroll
    for (int q = 0; q < 2; ++q) {
      int c = wid * 2 + q;  // chunk 0..15 (16 rows each)
      const char* srcA = (const char*)A + (size_t)(m0 + c * 16 + crow) * rb +
                         (size_t)t * 64 + slotg * 16;
      __builtin_amdgcn_global_load_lds((gvp)srcA, (svp)(dst + c * 1024), 16, 0,
                                       0);
    }
  };
  auto stageB = [&](int t) {
    char* dst = lds + ((unsigned)t % 3u) * 32768u + 16384u;
#pragma unroll
    for (int q = 0; q < 2; ++q) {
      int c = wid * 2 + q;
      const char* srcB = (const char*)BT + (size_t)(n0 + c * 16 + crow) * rb +
                         (size_t)t * 64 + slotg * 16;
      __builtin_amdgcn_global_load_lds((gvp)srcB, (svp)(dst + c * 1024), 16, 0,
                                       0);
    }
  };

  stageA(0);
  stageB(0);
  stageA(1);
  stageB(1);
  f32x4 acc[8][4] = {};
  int swcol = ((lg ^ ((lr >> 1) & 3)) * 16);
  for (int t = 0; t < NT; ++t) {
    if (t == NT - 1)
      asm volatile("s_waitcnt vmcnt(0)" ::: "memory");
    else
      asm volatile("s_waitcnt vmcnt(4)" ::: "memory");
    __builtin_amdgcn_s_barrier();
    __builtin_amdgcn_sched_barrier(0);
    const char* Ab = lds + ((unsigned)t % 3u) * 32768u;
    const char* Bb = Ab + 16384;
    int tn = t + 2;
    bool st = tn < NT;
    // ---- phase A ----
    bf16x8 bfr[4], afA[4], afB[4];
#pragma unroll
    for (int j = 0; j < 4; ++j)
      bfr[j] = *(const bf16x8*)(Bb + (wcN + j * 16 + lr) * 64 + swcol);
#pragma unroll
    for (int i = 0; i < 4; ++i)
      afA[i] = *(const bf16x8*)(Ab + (wrM + i * 16 + lr) * 64 + swcol);
    if (st) stageA(tn);
    __builtin_amdgcn_s_barrier();
    __builtin_amdgcn_sched_barrier(0);
    __builtin_amdgcn_s_setprio(1);
#pragma unroll
    for (int i = 0; i < 4; ++i)
#pragma unroll
      for (int j = 0; j < 4; ++j)
        acc[i][j] = __builtin_amdgcn_mfma_f32_16x16x32_bf16(afA[i], bfr[j],
                                                            acc[i][j], 0, 0, 0);
    __builtin_amdgcn_s_setprio(0);
    __builtin_amdgcn_sched_barrier(0);
    // ---- phase B ----
#pragma unroll
    for (int i = 0; i < 4; ++i)
      afB[i] = *(const bf16x8*)(Ab + (wrM + 64 + i * 16 + lr) * 64 + swcol);
    if (st) stageB(tn);
    __builtin_amdgcn_s_barrier();
    __builtin_amdgcn_sched_barrier(0);
    __builtin_amdgcn_s_setprio(1);
#pragma unroll
    for (int i = 0; i < 4; ++i)
#pragma unroll
      for (int j = 0; j < 4; ++j)
        acc[4 + i][j] = __builtin_amdgcn_mfma_f32_16x16x32_bf16(
            afB[i], bfr[j], acc[4 + i][j], 0, 0, 0);
    __builtin_amdgcn_s_setprio(0);
    __builtin_amdgcn_sched_barrier(0);
  }
#pragma unroll
  for (int i = 0; i < 8; ++i) {
#pragma unroll
    for (int j = 0; j < 4; ++j) {
#pragma unroll
      for (int r = 0; r < 4; ++r) {
        int row = m0 + wrM + i * 16 + lg * 4 + r;
        int col = n0 + wcN + j * 16 + lr;
        float v = acc[i][j][r];
        if (EPI == 0) {
          int which = col >> 10, cc = col & 1023;
          int b = row >> 11, tt = row & 2047, h = cc >> 6, d = cc & 63;
          bf16* dst = Cb + (size_t)which * 8388608;
          dst[((size_t)((b << 4) + h) * TSEQ + tt) * HEAD_DIM + d] = (bf16)v;
        } else {
          size_t o = (size_t)row * N + col;
          float u = v + bias[col];
          Cb[o] = (bf16)(u > 0.f ? u : 0.f);
        }
      }
    }
  }
}

// ---------------- 256x128 GEMM + residual epilogue (fp32 out), 2-phase pipeline ----------
__global__ __launch_bounds__(512, 2) void gemm_res(
    const bf16* __restrict__ A, const bf16* __restrict__ BT,
    float* __restrict__ Cf, const float* __restrict__ bias,
    const float* __restrict__ resid, int M, int N, int K) {
  __shared__ __attribute__((aligned(16))) char lds[73728];  // 3 x 24KB
  int gx = gridDim.x;
  int nwg = gx * gridDim.y;
  int wgid = blockIdx.y * gx + blockIdx.x;
  int cpx = nwg >> 3;
  int swz = (wgid & 7) * cpx + (wgid >> 3);
  int m0 = (swz / gx) * 256, n0 = (swz % gx) * 128;
  int tid = threadIdx.x;
  int lane = tid & 63, wid = tid >> 6;
  int lr = lane & 15, lg = lane >> 4;
  int wrM = (wid >> 1) * 64;  // wave M base: 0/64/128/192
  int wcN = (wid & 1) * 64;   // wave N base: 0/64
  int crow = lane >> 2;
  int slotg = (lane & 3) ^ ((crow >> 1) & 3);
  int NT = K >> 5;
  size_t rb = (size_t)K * 2;

  auto stageA = [&](int t) {
    char* dst = lds + ((unsigned)t % 3u) * 24576u;
#pragma unroll
    for (int q = 0; q < 2; ++q) {
      int c = wid * 2 + q;  // chunk 0..15 (16 rows each)
      const char* srcA = (const char*)A + (size_t)(m0 + c * 16 + crow) * rb +
                         (size_t)t * 64 + slotg * 16;
      __builtin_amdgcn_global_load_lds((gvp)srcA, (svp)(dst + c * 1024), 16, 0,
                                       0);
    }
  };
  auto stageB = [&](int t) {
    char* dst = lds + ((unsigned)t % 3u) * 24576u + 16384u;
    const char* srcB = (const char*)BT + (size_t)(n0 + wid * 16 + crow) * rb +
                       (size_t)t * 64 + slotg * 16;
    __builtin_amdgcn_global_load_lds((gvp)srcB, (svp)(dst + wid * 1024), 16, 0,
                                     0);
  };

  stageA(0);
  stageB(0);
  stageA(1);
  stageB(1);
  f32x4 acc[4][4] = {};
  int swcol = ((lg ^ ((lr >> 1) & 3)) * 16);
  for (int t = 0; t < NT; ++t) {
    if (t == NT - 1)
      asm volatile("s_waitcnt vmcnt(0)" ::: "memory");
    else
      asm volatile("s_waitcnt vmcnt(3)" ::: "memory");
    __builtin_amdgcn_s_barrier();
    __builtin_amdgcn_sched_barrier(0);
    const char* Ab = lds + ((unsigned)t % 3u) * 24576u;
    const char* Bb = Ab + 16384;
    int tn = t + 2;
    bool st = tn < NT;
    // ---- phase A ----
    bf16x8 bfr[4], afA[2], afB[2];
#pragma unroll
    for (int j = 0; j < 4; ++j)
      bfr[j] = *(const bf16x8*)(Bb + (wcN + j * 16 + lr) * 64 + swcol);
#pragma unroll
    for (int i = 0; i < 2; ++i)
      afA[i] = *(const bf16x8*)(Ab + (wrM + i * 16 + lr) * 64 + swcol);
    if (st) stageA(tn);
    __builtin_amdgcn_s_barrier();
    __builtin_amdgcn_sched_barrier(0);
    __builtin_amdgcn_s_setprio(1);
#pragma unroll
    for (int i = 0; i < 2; ++i)
#pragma unroll
      for (int j = 0; j < 4; ++j)
        acc[i][j] = __builtin_amdgcn_mfma_f32_16x16x32_bf16(afA[i], bfr[j],
                                                            acc[i][j], 0, 0, 0);
    __builtin_amdgcn_s_setprio(0);
    __builtin_amdgcn_sched_barrier(0);
    // ---- phase B ----
#pragma unroll
    for (int i = 0; i < 2; ++i)
      afB[i] = *(const bf16x8*)(Ab + (wrM + 32 + i * 16 + lr) * 64 + swcol);
    if (st) stageB(tn);
    __builtin_amdgcn_s_barrier();
    __builtin_amdgcn_sched_barrier(0);
    __builtin_amdgcn_s_setprio(1);
#pragma unroll
    for (int i = 0; i < 2; ++i)
#pragma unroll
      for (int j = 0; j < 4; ++j)
        acc[2 + i][j] = __builtin_amdgcn_mfma_f32_16x16x32_bf16(
            afB[i], bfr[j], acc[2 + i][j], 0, 0, 0);
    __builtin_amdgcn_s_setprio(0);
    __builtin_amdgcn_sched_barrier(0);
  }
#pragma unroll
  for (int i = 0; i < 4; ++i) {
#pragma unroll
    for (int j = 0; j < 4; ++j) {
#pragma unroll
      for (int r = 0; r < 4; ++r) {
        int row = m0 + wrM + i * 16 + lg * 4 + r;
        int col = n0 + wcN + j * 16 + lr;
        size_t o = (size_t)row * N + col;
        Cf[o] = resid[o] + bias[col] + acc[i][j][r];
      }
    }
  }
}

// ---------------- causal flash attention: swapped-QK 32x32, in-register P,
// double-buffered K/V, hardware permlane32_swap half-exchange (R16 best) --------------
// grid (64,16) x 256 threads: x = bh (XCD L2 locality), y -> Q = 15-y.
__global__ __launch_bounds__(256) void attn_kernel(
    const bf16* __restrict__ q, const bf16* __restrict__ k,
    const bf16* __restrict__ vt, bf16* __restrict__ out) {
  __shared__ __attribute__((aligned(16))) char ldsK[2][8192];
  __shared__ __attribute__((aligned(16))) char ldsV[2][8192];
  int bh = blockIdx.x;
  int b = bh >> 4, h = bh & 15;
  const bf16* qb = q + (size_t)bh * TSEQ * HEAD_DIM;
  const bf16* kb = k + (size_t)bh * TSEQ * HEAD_DIM;
  const bf16* vb = vt + (size_t)bh * HEAD_DIM * TSEQ;
  int tid = threadIdx.x, lane = tid & 63, w = tid >> 6;
  int l31 = lane & 31, hi = lane >> 5;
  int Q = 15 - blockIdx.y;    // supertile of 128 rows; longest job first
  int tw = Q * 128 + w * 32;  // wave's 32 q-rows
  int qrow = tw + l31;        // this lane's q-row (swapped layout)
  int srow0 = tid >> 3;       // staging rows 0..31 (i=0), +32 (i=1)
  int scol = (tid & 7) * 16;  // byte col
  int swz31 = (l31 & 7) << 4; // read-side swizzle for rows l31 / 32+l31
  bf16x8 aq[4];
#pragma unroll
  for (int f = 0; f < 4; ++f)
    aq[f] = *(const bf16x8*)&qb[(size_t)qrow * HEAD_DIM + f * 16 + hi * 8];
  f32x16 o0 = {}, o1 = {};
  f32x16 minit;
#pragma unroll
  for (int i = 0; i < 16; ++i) minit[i] = -8.0f;  // softmax shift in C-init
  float sacc = 0.f;
  int nj = 2 * Q + 2;

  bf16x8 krg[2], vrg[2];
  auto loadKV = [&](int j) {
#pragma unroll
    for (int i = 0; i < 2; ++i) {
      int rr = srow0 + i * 32;
      krg[i] =
          *(const bf16x8*)&kb[(size_t)(j * 64 + rr) * HEAD_DIM + (scol >> 1)];
      vrg[i] = *(const bf16x8*)&vb[(size_t)rr * TSEQ + j * 64 + (scol >> 1)];
    }
  };
  auto writeKV = [&](int buf) {
#pragma unroll
    for (int i = 0; i < 2; ++i) {
      int rr = srow0 + i * 32;
      int sw = scol ^ ((rr & 7) << 4);
      *(bf16x8*)(ldsK[buf] + rr * 128 + sw) = krg[i];
      *(bf16x8*)(ldsV[buf] + rr * 128 + sw) = vrg[i];
    }
  };

  loadKV(0);
  writeKV(0);
  __syncthreads();
  for (int j = 0; j < nj; ++j) {
    bool more = j + 1 < nj;
    if (more) loadKV(j + 1);  // issue early: HBM hides under compute
    const char* K0 = ldsK[j & 1];
    const char* V0 = ldsV[j & 1];
    if (j * 64 <= tw + 31) {  // wave-uniform: skip fully-masked tiles
      f32x16 s0 = minit, s1 = minit;
      __builtin_amdgcn_s_setprio(1);
#pragma unroll
      for (int f = 0; f < 4; ++f) {
        int colb = (f * 32 + hi * 16) ^ swz31;
        bf16x8 ka = *(const bf16x8*)(K0 + l31 * 128 + colb);
        bf16x8 kb2 = *(const bf16x8*)(K0 + (32 + l31) * 128 + colb);
        s0 = __builtin_amdgcn_mfma_f32_32x32x16_bf16(ka, aq[f], s0, 0, 0, 0);
        s1 = __builtin_amdgcn_mfma_f32_32x32x16_bf16(kb2, aq[f], s1, 0, 0, 0);
      }
      __builtin_amdgcn_s_setprio(0);
      if (j >= 2 * Q) {  // causal mask on boundary tiles
#pragma unroll
        for (int reg = 0; reg < 16; ++reg) {
          int key = j * 64 + (reg & 3) + 8 * (reg >> 2) + 4 * hi;
          if (key > qrow) s0[reg] = -1e30f;
          if (key + 32 > qrow) s1[reg] = -1e30f;
        }
      }
      unsigned pk0[8], pk1[8];
#pragma unroll
      for (int p = 0; p < 8; ++p) {
        float a0 = exp2f(s0[2 * p]), b0 = exp2f(s0[2 * p + 1]);
        float a1 = exp2f(s1[2 * p]), b1 = exp2f(s1[2 * p + 1]);
        sacc += (a0 + b0) + (a1 + b1);
        pk0[p] = pk2(a0, b0);
        pk1[p] = pk2(a1, b1);
      }
      // Half-exchange via HW permlane32_swap (VALU crossbar, no LDS):
      // swap(x0,x2): x0' = [own_lo | partner_lo] = pa.u[0],
      //              x2' = [partner_hi | own_hi] = pa.u[2]. Same for (x1,x3).
      __builtin_amdgcn_s_setprio(1);
#pragma unroll
      for (int ks = 0; ks < 4; ++ks) {
        const unsigned* P = (ks >> 1) ? pk1 : pk0;
        int kp = (ks & 1) * 4;
        unsigned x0 = P[kp + 0], x1 = P[kp + 1];
        unsigned x2 = P[kp + 2], x3 = P[kp + 3];
        asm("v_permlane32_swap_b32 %0, %1" : "+v"(x0), "+v"(x2));
        asm("v_permlane32_swap_b32 %0, %1" : "+v"(x1), "+v"(x3));
        union { unsigned u[4]; bf16x8 v; } pa;
        pa.u[0] = x0;
        pa.u[1] = x1;
        pa.u[2] = x2;
        pa.u[3] = x3;
        int colb = (ks * 32 + hi * 16) ^ swz31;
        bf16x8 bv0 = *(const bf16x8*)(V0 + l31 * 128 + colb);
        bf16x8 bv1 = *(const bf16x8*)(V0 + (32 + l31) * 128 + colb);
        o0 = __builtin_amdgcn_mfma_f32_32x32x16_bf16(pa.v, bv0, o0, 0, 0, 0);
        o1 = __builtin_amdgcn_mfma_f32_32x32x16_bf16(pa.v, bv1, o1, 0, 0, 0);
      }
      __builtin_amdgcn_s_setprio(0);
    }
    if (more) writeKV((j + 1) & 1);  // write-late: after compute
    __syncthreads();
  }
  float tot = sacc + __shfl_xor(sacc, 32);
#pragma unroll
  for (int reg = 0; reg < 16; ++reg) {
    int ql = (reg & 3) + 8 * (reg >> 2) + 4 * hi;
    float lw = __shfl(tot, ql);
    float rl = 1.0f / lw;
    int t = tw + ql;
    size_t o = ((size_t)(b * TSEQ) + t) * EMBED + h * HEAD_DIM;
    out[o + l31] = (bf16)(o0[reg] * rl);
    out[o + 32 + l31] = (bf16)(o1[reg] * rl);
  }
}

// ---------------- launch ----------------
extern "C" void kernel_launch(void* const* d_in, const int* in_sizes, int n_in,
                              void* d_out, int out_size, void* d_ws,
                              size_t ws_size, hipStream_t stream) {
  const float* x = (const float*)d_in[0];
  const float* Wq = (const float*)d_in[1];
  const float* Wk = (const float*)d_in[2];
  const float* Wv = (const float*)d_in[3];
  const float* Wo = (const float*)d_in[4];
  const float* bo = (const float*)d_in[5];
  const float* W1 = (const float*)d_in[6];
  const float* b1 = (const float*)d_in[7];
  const float* W2 = (const float*)d_in[8];
  const float* b2 = (const float*)d_in[9];
  const float* g1 = (const float*)d_in[10];
  const float* be1 = (const float*)d_in[11];
  const float* g2 = (const float*)d_in[12];
  const float* be2 = (const float*)d_in[13];
  float* out = (float*)d_out;
  char* ws = (char*)d_ws;

  const size_t U = 16777216;  // 16 MiB
  bf16* h = (bf16*)(ws + 0 * U);
  bf16* qb = (bf16*)(ws + 1 * U);
  bf16* vtb = (bf16*)(ws + 0 * U);
  bf16* vnb = (bf16*)(ws + 3 * U);
  bf16* ao = (bf16*)(ws + 3 * U);
  float* x1 = (float*)(ws + 4 * U);
  bf16* h2 = (bf16*)(ws + 6 * U);
  bf16* ff1 = (bf16*)(ws + 0 * U);
  char* wbase = ws + 7 * U;
  bf16* WqkvT = (bf16*)(wbase);           // 6 MB
  bf16* WoT = (bf16*)(wbase + 6291456);   // 2 MB
  bf16* W1T = (bf16*)(wbase + 8388608);   // 8 MB
  bf16* W2T = (bf16*)(wbase + 16777216);  // 8 MB

  hipLaunchKernelGGL(conv_wqkv_t, dim3(16, 16, 3), dim3(256), 0, stream, Wq,
                     Wk, Wv, WqkvT);
  hipLaunchKernelGGL(transpose_conv, dim3(16, 16), dim3(256), 0, stream, Wo,
                     WoT, 1024, 1024);
  hipLaunchKernelGGL(transpose_conv, dim3(64, 16), dim3(256), 0, stream, W1,
                     W1T, 1024, 4096);
  hipLaunchKernelGGL(transpose_conv, dim3(16, 64), dim3(256), 0, stream, W2,
                     W2T, 4096, 1024);
  hipLaunchKernelGGL(ln_kernel, dim3(8192), dim3(256), 0, stream, x, g1, be1,
                     h);
  // fused QKV projection: 256x256 2-phase pipelined GEMM, scatter epilogue
  hipLaunchKernelGGL((gemm256<0>), dim3(12, 32), dim3(512), 0, stream, h,
                     WqkvT, qb, (const float*)nullptr, ROWS, 3072, 1024);
  // v [B,H,T,D] -> vt [B,H,D,T]
  hipLaunchKernelGGL(transpose_v, dim3(32, 64), dim3(256), 0, stream, vnb,
                     vtb);
  // attention (swapped-QK 32x32, in-reg P, HW permlane32_swap; R16 config)
  hipLaunchKernelGGL(attn_kernel, dim3(64, 16), dim3(256), 0, stream, qb,
                     qb + 8388608, vtb, ao);
  // x1 = x + ao @ Wo + bo : 256x128 pipelined GEMM with residual epilogue
  hipLaunchKernelGGL(gemm_res, dim3(8, 32), dim3(512), 0, stream, ao, WoT, x1,
                     bo, x, ROWS, 1024, 1024);
  // h2 = LN2(x1)
  hipLaunchKernelGGL(ln_kernel, dim3(8192), dim3(256), 0, stream, x1, g2, be2,
                     h2);
  // ff1 = relu(h2 @ W1 + b1): 256x256 2-phase pipelined GEMM
  hipLaunchKernelGGL((gemm256<3>), dim3(16, 32), dim3(512), 0, stream, h2, W1T,
                     ff1, b1, ROWS, 4096, 1024);
  // out = x1 + ff1 @ W2 + b2 : 256x128 pipelined GEMM with residual epilogue
  hipLaunchKernelGGL(gemm_res, dim3(8, 32), dim3(512), 0, stream, ff1, W2T,
                     out, b2, x1, ROWS, 1024, 4096);
}